// Round 4
// baseline (365.864 us; speedup 1.0000x reference)
//
#include <hip/hip_runtime.h>

// ---------------- problem constants ----------------
#define BB 128
#define NN 4096
#define DD 64
#define SS 7
#define HH 128
#define N_ITERS 3
#define EPS_ATTN 1e-8f
#define LN_EPS 1e-5f
// scale = D^-0.5 = 0.125 (folded into WqkT)

typedef unsigned short ushortT;
using short8  = __attribute__((ext_vector_type(8))) short;
using floatx4 = __attribute__((ext_vector_type(4))) float;
using uint4v  = __attribute__((ext_vector_type(4))) unsigned;

__device__ __forceinline__ ushortT f2bf(float f) {
    unsigned x = __builtin_bit_cast(unsigned, f);
    x = x + 0x7fff + ((x >> 16) & 1);   // RNE
    return (ushortT)(x >> 16);
}
__device__ __forceinline__ void wave_stats64(float x, float& mu, float& var) {
    float s1 = x, s2 = x * x;
#pragma unroll
    for (int off = 32; off > 0; off >>= 1) {
        s1 += __shfl_xor(s1, off);
        s2 += __shfl_xor(s2, off);
    }
    mu  = s1 * (1.f / 64.f);
    var = s2 * (1.f / 64.f) - mu * mu;
}

// ---------------- prep: pack/transpose small weights ----------------
__global__ void prep_w(const float* __restrict__ Wih, const float* __restrict__ Whh,
                       const float* __restrict__ w1, const float* __restrict__ w2,
                       const float* __restrict__ Wv, const float* __restrict__ Wq,
                       const float* __restrict__ Wk,
                       float* __restrict__ WihT, float* __restrict__ WhhT,
                       float* __restrict__ w1T, float* __restrict__ w2T,
                       float* __restrict__ WvT, float* __restrict__ WqkT) {
    if (blockIdx.x >= 192) {
        // WqkT[d][t] = 0.125 * sum_e Wk[e][t]*Wq[e][d]  (qk_t = sum_d xn_d * WqkT[d][t])
        int idx = (blockIdx.x - 192) * 256 + threadIdx.x;   // 0..4095
        int d = idx >> 6, tt = idx & 63;
        float acc = 0.f;
#pragma unroll 8
        for (int e = 0; e < 64; ++e) acc += Wk[e * 64 + tt] * Wq[e * 64 + d];
        WqkT[d * 64 + tt] = 0.125f * acc;
        return;
    }
    int i = blockIdx.x * 256 + threadIdx.x;   // < 49152
    if (i < 12288) {
        int e = i >> 6, d = i & 63;
        WihT[d * 192 + e] = Wih[i];
    } else if (i < 24576) {
        int j = i - 12288; int e = j >> 6, d = j & 63;
        WhhT[d * 192 + e] = Whh[j];
    } else if (i < 32768) {
        int j = i - 24576; int e = j >> 6, d = j & 63;   // w1 [128][64]
        w1T[d * 128 + e] = w1[j];
    } else if (i < 40960) {
        int j = i - 32768; int e = j >> 7, h = j & 127;  // w2 [64][128]
        w2T[h * 64 + e] = w2[j];
    } else if (i < 45056) {
        int j = i - 40960; int d = j >> 6, e = j & 63;   // Wv [d][e] -> WvT [e][d]
        WvT[e * 64 + d] = Wv[j];
    }
}

// ---------------- once: input LN -> bf16 pack (pure streaming) ----------------
// Same row/lane mapping as attn: block ck = 128 rows, wave w rows w*32..+32,
// lane (m,qd): rows {w*32+tile*16+m}, dims {c*32+qd*8..+8}.
__global__ __launch_bounds__(256, 2) void ln_pack(
    const float* __restrict__ x,
    const float* __restrict__ lng, const float* __restrict__ lnb,
    ushortT* __restrict__ xnf) {
    int t = threadIdx.x;
    int ck = blockIdx.x;
    int w = t >> 6, lane = t & 63, m = lane & 15, qd = lane >> 4;
    float4 g4[2][2], b4[2][2];
#pragma unroll
    for (int c = 0; c < 2; ++c) {
        g4[c][0] = *reinterpret_cast<const float4*>(lng + c * 32 + qd * 8);
        g4[c][1] = *reinterpret_cast<const float4*>(lng + c * 32 + qd * 8 + 4);
        b4[c][0] = *reinterpret_cast<const float4*>(lnb + c * 32 + qd * 8);
        b4[c][1] = *reinterpret_cast<const float4*>(lnb + c * 32 + qd * 8 + 4);
    }
#pragma unroll
    for (int tile = 0; tile < 2; ++tile) {
        long R = (long)ck * 128 + w * 32 + tile * 16 + m;
        float4 xa[2][2];
#pragma unroll
        for (int c = 0; c < 2; ++c) {
            xa[c][0] = *reinterpret_cast<const float4*>(x + R * 64 + c * 32 + qd * 8);
            xa[c][1] = *reinterpret_cast<const float4*>(x + R * 64 + c * 32 + qd * 8 + 4);
        }
        float s1 = 0.f, s2 = 0.f;
#pragma unroll
        for (int c = 0; c < 2; ++c)
#pragma unroll
            for (int h = 0; h < 2; ++h) {
                float4 v = xa[c][h];
                s1 += v.x + v.y + v.z + v.w;
                s2 += v.x * v.x + v.y * v.y + v.z * v.z + v.w * v.w;
            }
        s1 += __shfl_xor(s1, 16); s2 += __shfl_xor(s2, 16);
        s1 += __shfl_xor(s1, 32); s2 += __shfl_xor(s2, 32);
        float mu = s1 * (1.f / 64.f);
        float var = s2 * (1.f / 64.f) - mu * mu;
        float rs = rsqrtf(var + LN_EPS);
        unsigned xwt[8];
#pragma unroll
        for (int c = 0; c < 2; ++c)
#pragma unroll
            for (int h = 0; h < 2; ++h) {
                float n0 = (xa[c][h].x - mu) * rs * g4[c][h].x + b4[c][h].x;
                float n1 = (xa[c][h].y - mu) * rs * g4[c][h].y + b4[c][h].y;
                float n2 = (xa[c][h].z - mu) * rs * g4[c][h].z + b4[c][h].z;
                float n3 = (xa[c][h].w - mu) * rs * g4[c][h].w + b4[c][h].w;
                xwt[c * 4 + h * 2]     = (unsigned)f2bf(n0) | ((unsigned)f2bf(n1) << 16);
                xwt[c * 4 + h * 2 + 1] = (unsigned)f2bf(n2) | ((unsigned)f2bf(n3) << 16);
            }
        ushortT* xp = xnf + (long)ck * 8192 + w * 2048 + tile * 1024 + lane * 16;
        *reinterpret_cast<uint4*>(xp) = make_uint4(xwt[0], xwt[1], xwt[2], xwt[3]);
        *reinterpret_cast<uint4*>(xp + 8) = make_uint4(xwt[4], xwt[5], xwt[6], xwt[7]);
    }
}

// ---------------- per-iter: attention, fully MFMA (lean, no LN branch) ------
// One block = one 128-row chunk (grid 4096; b = ck>>5). 256 thr, 4 waves.
// Phase 1: logits via mfma(A=qk_bf frag from global, B=xn regs); both tiles,
// then shfl_xor(32) hands tile-1 rows to lanes qd>=2 so every lane does ONE
// row's 7-slot softmax. p -> p_lds bf16 [slot][row].
// xn -> xnT LDS [e]*140+row via pair-packed ds_write_b32.
// Phase 2: pxn[s][e] = mfma(A=p_lds frag, B=xnT b64-pair frags);
// den[s] = mfma(A=p_lds frag, B=ones) accumulated alongside (w0,m0 stores).
__global__ __launch_bounds__(256, 4) void attn_kernel(
    const ushortT* __restrict__ xnf,
    const ushortT* __restrict__ qk_bf,   // [b][slot 8][dim 64] bf16, slot7=0
    float* __restrict__ pxn_p, float* __restrict__ den_p) {
    int t = threadIdx.x;
    int ck = blockIdx.x, b = ck >> 5;
    int w = t >> 6, lane = t & 63, m = lane & 15, qd = lane >> 4;
    __shared__ __align__(16) ushortT xnT[64 * 140];      // [e]*140 + row
    __shared__ __align__(16) ushortT p_lds[16][136];     // [slot][row]; slots 7..15 unused

    // ---- A-frags: qk^T, slots x dims, straight from global (L2) ----
    short8 aq0 = {}, aq1 = {};
    if (m < 8) {
        const ushortT* qb = qk_bf + b * 512 + m * 64 + qd * 8;
        aq0 = *reinterpret_cast<const short8*>(qb);        // dims qd*8..+8
        aq1 = *reinterpret_cast<const short8*>(qb + 32);   // dims 32+qd*8..+8
    }

    unsigned xw[2][8];   // [tile][word]: words 0-3 = c0 dims, 4-7 = c1 dims
#pragma unroll
    for (int tile = 0; tile < 2; ++tile) {
        const ushortT* xp = xnf + (long)ck * 8192 + w * 2048 + tile * 1024 + lane * 16;
        uint4 u0 = *reinterpret_cast<const uint4*>(xp);
        uint4 u1 = *reinterpret_cast<const uint4*>(xp + 8);
        xw[tile][0] = u0.x; xw[tile][1] = u0.y; xw[tile][2] = u0.z; xw[tile][3] = u0.w;
        xw[tile][4] = u1.x; xw[tile][5] = u1.y; xw[tile][6] = u1.z; xw[tile][7] = u1.w;
    }

    // ---- stash xn into transposed LDS via pair-packed b32 writes:
    //      lanes m, m^1 hold rows R, R^1; exchange words with shfl_xor(1),
    //      even lane writes dim-quads 0-3, odd lane 4-7, both rows each ----
#pragma unroll
    for (int tile = 0; tile < 2; ++tile) {
        int Re = (w * 32 + tile * 16 + m) & ~1;
#pragma unroll
        for (int c = 0; c < 2; ++c) {
            unsigned pt[4];
#pragma unroll
            for (int k = 0; k < 4; ++k) pt[k] = __shfl_xor(xw[tile][c * 4 + k], 1);
#pragma unroll
            for (int kk = 0; kk < 2; ++kk) {
                unsigned own = (m & 1) ? xw[tile][c * 4 + 2 + kk] : xw[tile][c * 4 + kk];
                unsigned par = (m & 1) ? pt[2 + kk] : pt[kk];
                unsigned a   = (m & 1) ? par : own;   // even-row value
                unsigned bb  = (m & 1) ? own : par;   // odd-row value
                unsigned lo = (a & 0xffffu) | (bb << 16);           // dim e
                unsigned hi = (a >> 16)     | (bb & 0xffff0000u);   // dim e+1
                int e = c * 32 + qd * 8 + 2 * kk + ((m & 1) ? 4 : 0);
                *reinterpret_cast<unsigned*>(&xnT[e * 140 + Re])       = lo;
                *reinterpret_cast<unsigned*>(&xnT[(e + 1) * 140 + Re]) = hi;
            }
        }
    }

    // ---- phase 1: logits for both tiles ----
    floatx4 accT0 = {0.f, 0.f, 0.f, 0.f}, accT1 = {0.f, 0.f, 0.f, 0.f};
    {
        uint4v b00 = {xw[0][0], xw[0][1], xw[0][2], xw[0][3]};
        uint4v b01 = {xw[0][4], xw[0][5], xw[0][6], xw[0][7]};
        accT0 = __builtin_amdgcn_mfma_f32_16x16x32_bf16(aq0,
                    __builtin_bit_cast(short8, b00), accT0, 0, 0, 0);
        accT0 = __builtin_amdgcn_mfma_f32_16x16x32_bf16(aq1,
                    __builtin_bit_cast(short8, b01), accT0, 0, 0, 0);
        uint4v b10 = {xw[1][0], xw[1][1], xw[1][2], xw[1][3]};
        uint4v b11 = {xw[1][4], xw[1][5], xw[1][6], xw[1][7]};
        accT1 = __builtin_amdgcn_mfma_f32_16x16x32_bf16(aq0,
                    __builtin_bit_cast(short8, b10), accT1, 0, 0, 0);
        accT1 = __builtin_amdgcn_mfma_f32_16x16x32_bf16(aq1,
                    __builtin_bit_cast(short8, b11), accT1, 0, 0, 0);
    }

    // ---- tile-split: qd<2 keeps tile0, qd>=2 receives tile1 (real slots);
    //      then qd-pair exchange gives each lane all 7 slots of ONE row ----
    float lgA[4], lgB[4];
#pragma unroll
    for (int r = 0; r < 4; ++r) {
        float hi = __shfl_xor(accT1[r], 32);
        float wk = (qd < 2) ? accT0[r] : hi;   // slots (qd&1)*4 + r of my row
        float pr = __shfl_xor(wk, 16);
        lgA[r] = (qd & 1) ? pr : wk;           // slots 0-3
        lgB[r] = (qd & 1) ? wk : pr;           // slots 4-7 (7 excluded below)
    }
    float mx = fmaxf(fmaxf(fmaxf(lgA[0], lgA[1]), fmaxf(lgA[2], lgA[3])),
                     fmaxf(fmaxf(lgB[0], lgB[1]), lgB[2]));
    float eA[4], eB[3], sum = 0.f;
#pragma unroll
    for (int r = 0; r < 4; ++r) { eA[r] = __expf(lgA[r] - mx); sum += eA[r]; }
#pragma unroll
    for (int r = 0; r < 3; ++r) { eB[r] = __expf(lgB[r] - mx); sum += eB[r]; }
    float inv = 1.f / sum;
    int prow = w * 32 + (qd >> 1) * 16 + m;
    if ((qd & 1) == 0) {
#pragma unroll
        for (int r = 0; r < 4; ++r) p_lds[r][prow] = f2bf(eA[r] * inv + EPS_ATTN);
    } else {
#pragma unroll
        for (int r = 0; r < 3; ++r) p_lds[4 + r][prow] = f2bf(eB[r] * inv + EPS_ATTN);
    }
    __syncthreads();

    // ---- phase 2: pxn[s][e] and den[s] via MFMA; wave w owns e-tile w*16..+16 ----
    short8 ones;
#pragma unroll
    for (int j = 0; j < 8; ++j) ones[j] = (short)0x3F80;   // bf16 1.0

    floatx4 acc2 = {0.f, 0.f, 0.f, 0.f}, accd = {0.f, 0.f, 0.f, 0.f};
#pragma unroll
    for (int ks = 0; ks < 4; ++ks) {
        short8 ap = *reinterpret_cast<const short8*>(&p_lds[m][ks * 32 + qd * 8]);
        const ushortT* xp = xnT + (w * 16 + m) * 140 + ks * 32 + qd * 8;
        uint2 u0 = *reinterpret_cast<const uint2*>(xp);
        uint2 u1 = *reinterpret_cast<const uint2*>(xp + 4);
        uint4v bb = {u0.x, u0.y, u1.x, u1.y};
        acc2 = __builtin_amdgcn_mfma_f32_16x16x32_bf16(ap,
                   __builtin_bit_cast(short8, bb), acc2, 0, 0, 0);
        accd = __builtin_amdgcn_mfma_f32_16x16x32_bf16(ap, ones, accd, 0, 0, 0);
    }
#pragma unroll
    for (int r = 0; r < 4; ++r) {
        int s = qd * 4 + r;
        if (s < 7) pxn_p[((long)ck * 7 + s) * 64 + w * 16 + m] = acc2[r];
    }
    if (w == 0 && m == 0) {
#pragma unroll
        for (int r = 0; r < 4; ++r) {
            int s = qd * 4 + r;
            if (s < 7) den_p[ck * 8 + s] = accd[r];
        }
    }
}

// ---------------- per-slot pipeline ----------------
// 896 blocks (one per (b,s)), 192 threads (3 waves).
__global__ __launch_bounds__(192) void slot_update_q(
    int mode,
    const float* __restrict__ pxn_p, const float* __restrict__ den_p,
    float* __restrict__ slots,
    const float* __restrict__ nbg, const float* __restrict__ nfg,
    const float* __restrict__ bgmu, const float* __restrict__ bgls,
    const float* __restrict__ fmu, const float* __restrict__ fls,
    const float* __restrict__ WihT, const float* __restrict__ WhhT,
    const float* __restrict__ bih, const float* __restrict__ bhh,
    const float* __restrict__ lng, const float* __restrict__ lnb,
    const float* __restrict__ w1T, const float* __restrict__ b1,
    const float* __restrict__ w2T, const float* __restrict__ b2,
    const float* __restrict__ WvT, const float* __restrict__ WqkT,
    const float* __restrict__ sg, const float* __restrict__ sb,
    ushortT* __restrict__ qk_bf, float* __restrict__ outp) {
    int bs = blockIdx.x, t = threadIdx.x;
    int b = bs / 7, s = bs % 7;
    __shared__ float pxnL[64], hprevL[64], updL[64], giL[192], ghL[192],
                     mnL[64], m1L[128], xnL[64];
    __shared__ float denL;
    float res = 0.f;
    if (mode == 0) {
        if (t < 64) {
            if (s == 0) res = bgmu[t] + __expf(bgls[t]) * nbg[b * 64 + t];
            else        res = fmu[t]  + __expf(fls[t])  * nfg[(b * 6 + s - 1) * 64 + t];
        }
    } else {
        // stage a: wave0 = pxn chunk-reduce; wave1(lo) = den; wave2 = hprev
        if (t < 64) {
            float psum = 0.f;
#pragma unroll 16
            for (int c = 0; c < 32; ++c)
                psum += pxn_p[((long)(b * 32 + c) * 7 + s) * 64 + t];
            pxnL[t] = psum;
        } else if (t < 96) {
            float dv = den_p[(b * 32 + (t - 64)) * 8 + s];
#pragma unroll
            for (int off = 16; off > 0; off >>= 1) dv += __shfl_xor(dv, off, 32);
            if (t == 64) denL = dv;
        } else if (t >= 128) {
            hprevL[t - 128] = slots[bs * 64 + (t - 128)];
        }
        __syncthreads();
        if (t < 64) {
            float nm = 0.f;
#pragma unroll 8
            for (int e = 0; e < 64; ++e) nm += pxnL[e] * WvT[e * 64 + t];
            updL[t] = nm / denL;
        }
        __syncthreads();
        {   // GRU gates, 192-wide
            float a = bih[t], h2 = bhh[t];
#pragma unroll 8
            for (int d = 0; d < 64; ++d) {
                a  += updL[d]   * WihT[d * 192 + t];
                h2 += hprevL[d] * WhhT[d * 192 + t];
            }
            giL[t] = a; ghL[t] = h2;
        }
        __syncthreads();
        if (t < 64) {
            float r = 1.f / (1.f + __expf(-(giL[t] + ghL[t])));
            float z = 1.f / (1.f + __expf(-(giL[64 + t] + ghL[64 + t])));
            float n = tanhf(giL[128 + t] + r * ghL[128 + t]);
            float h = (1.f - z) * n + z * hprevL[t];
            res = h;
            float mu, var;
            wave_stats64(h, mu, var);
            mnL[t] = (h - mu) * rsqrtf(var + LN_EPS) * lng[t] + lnb[t];
        }
        __syncthreads();
        if (t < 128) {
            float a = b1[t];
#pragma unroll 8
            for (int d = 0; d < 64; ++d) a += mnL[d] * w1T[d * 128 + t];
            m1L[t] = fmaxf(a, 0.f);
        }
        __syncthreads();
        if (t < 64) {
            float a = b2[t];
#pragma unroll 8
            for (int h2 = 0; h2 < 128; ++h2) a += m1L[h2] * w2T[h2 * 64 + t];
            res += a;
        }
    }
    if (t < 64) slots[bs * 64 + t] = res;
    if (mode == 2) {
        if (t < 64) outp[bs * 64 + t] = res;
        return;
    }
    // slot LN -> qk = (0.125 * Wk^T Wq) xn, stored bf16 [b][slot][dim]
    if (t < 64) {
        float mu, var;
        wave_stats64(res, mu, var);
        xnL[t] = (res - mu) * rsqrtf(var + LN_EPS) * sg[t] + sb[t];
    }
    __syncthreads();
    if (t < 64) {
        float qk = 0.f;
#pragma unroll 8
        for (int d = 0; d < 64; ++d) qk += xnL[d] * WqkT[d * 64 + t];
        qk_bf[b * 512 + s * 64 + t] = f2bf(qk);
        if (s == 0) qk_bf[b * 512 + 7 * 64 + t] = 0;
    }
}

// ---------------- launcher ----------------
extern "C" void kernel_launch(void* const* d_in, const int* in_sizes, int n_in,
                              void* d_out, int out_size, void* d_ws, size_t ws_size,
                              hipStream_t stream) {
    const float* inputs    = (const float*)d_in[0];
    const float* noise_bg  = (const float*)d_in[1];
    const float* noise_fg  = (const float*)d_in[2];
    const float* ln_in_g   = (const float*)d_in[3];
    const float* ln_in_b   = (const float*)d_in[4];
    const float* ln_slot_g = (const float*)d_in[5];
    const float* ln_slot_b = (const float*)d_in[6];
    const float* ln_mlp_g  = (const float*)d_in[7];
    const float* ln_mlp_b  = (const float*)d_in[8];
    const float* Wq        = (const float*)d_in[9];
    const float* Wk        = (const float*)d_in[10];
    const float* Wv        = (const float*)d_in[11];
    const float* W_ih      = (const float*)d_in[12];
    const float* W_hh      = (const float*)d_in[13];
    const float* b_ih      = (const float*)d_in[14];
    const float* b_hh      = (const float*)d_in[15];
    const float* mlp_w1    = (const float*)d_in[16];
    const float* mlp_b1    = (const float*)d_in[17];
    const float* mlp_w2    = (const float*)d_in[18];
    const float* mlp_b2    = (const float*)d_in[19];
    const float* sbg_mu    = (const float*)d_in[20];
    const float* sbg_ls    = (const float*)d_in[21];
    const float* s_mu      = (const float*)d_in[22];
    const float* s_ls      = (const float*)d_in[23];

    char* ws = (char*)d_ws;
    size_t off = 0;
    auto alloc = [&](size_t bytes) {
        void* p = ws + off;
        off += (bytes + 255) & ~(size_t)255;
        return p;
    };
    ushortT* xnf   = (ushortT*)alloc((size_t)BB * NN * 64 * 2);   // 64 MiB bf16 xn
    float* slots   = (float*)alloc(57344 * 4);
    ushortT* qk_bf = (ushortT*)alloc((size_t)BB * 512 * 2);       // [b][slot8][64] bf16
    float* pxn_p   = (float*)alloc((size_t)4096 * 7 * 64 * 4);    // 7.34 MB
    float* den_p   = (float*)alloc(4096 * 8 * 4);
    float* WihT    = (float*)alloc(12288 * 4);
    float* WhhT    = (float*)alloc(12288 * 4);
    float* w1T     = (float*)alloc(8192 * 4);
    float* w2T     = (float*)alloc(8192 * 4);
    float* WvT     = (float*)alloc(4096 * 4);
    float* WqkT    = (float*)alloc(4096 * 4);
    if (off > ws_size) return;

    prep_w<<<208, 256, 0, stream>>>(W_ih, W_hh, mlp_w1, mlp_w2, Wv, Wq, Wk,
                                    WihT, WhhT, w1T, w2T, WvT, WqkT);
    slot_update_q<<<896, 192, 0, stream>>>(0, pxn_p, den_p, slots,
                                           noise_bg, noise_fg, sbg_mu, sbg_ls,
                                           s_mu, s_ls, WihT, WhhT, b_ih, b_hh,
                                           ln_mlp_g, ln_mlp_b, w1T, mlp_b1,
                                           w2T, mlp_b2, WvT, WqkT,
                                           ln_slot_g, ln_slot_b,
                                           qk_bf, (float*)d_out);
    ln_pack<<<4096, 256, 0, stream>>>(inputs, ln_in_g, ln_in_b, xnf);
    for (int it = 0; it < N_ITERS; ++it) {
        attn_kernel<<<4096, 256, 0, stream>>>(xnf, qk_bf, pxn_p, den_p);
        slot_update_q<<<896, 192, 0, stream>>>((it == N_ITERS - 1) ? 2 : 1,
                                               pxn_p, den_p, slots,
                                               noise_bg, noise_fg, sbg_mu, sbg_ls,
                                               s_mu, s_ls, WihT, WhhT, b_ih, b_hh,
                                               ln_mlp_g, ln_mlp_b, w1T, mlp_b1,
                                               w2T, mlp_b2, WvT, WqkT,
                                               ln_slot_g, ln_slot_b,
                                               qk_bf, (float*)d_out);
    }
}

// Round 5
// 352.427 us; speedup vs baseline: 1.0381x; 1.0381x over previous
//
#include <hip/hip_runtime.h>
#include <hip/hip_cooperative_groups.h>
namespace cg = cooperative_groups;

// ---------------- problem constants ----------------
#define BB 128
#define NN 4096
#define DD 64
#define SS 7
#define HH 128
#define N_ITERS 3
#define EPS_ATTN 1e-8f
#define LN_EPS 1e-5f
// scale = D^-0.5 = 0.125 (folded into WqkT)

typedef unsigned short ushortT;
using short8  = __attribute__((ext_vector_type(8))) short;
using floatx4 = __attribute__((ext_vector_type(4))) float;
using uint4v  = __attribute__((ext_vector_type(4))) unsigned;

__device__ __forceinline__ ushortT f2bf(float f) {
    unsigned x = __builtin_bit_cast(unsigned, f);
    x = x + 0x7fff + ((x >> 16) & 1);   // RNE
    return (ushortT)(x >> 16);
}
__device__ __forceinline__ void wave_stats64(float x, float& mu, float& var) {
    float s1 = x, s2 = x * x;
#pragma unroll
    for (int off = 32; off > 0; off >>= 1) {
        s1 += __shfl_xor(s1, off);
        s2 += __shfl_xor(s2, off);
    }
    mu  = s1 * (1.f / 64.f);
    var = s2 * (1.f / 64.f) - mu * mu;
}

// ============================================================================
// Persistent cooperative kernel: prep -> slot0 -> 3x(attn, slot update).
// Grid 1024 x 256 (4 blocks/CU, co-resident). Block bid owns batch bt=bid>>3,
// chunks cgrp*4..+4 (512 rows); LN'd bf16 rows persist in regs (xw[4][2][8]).
// ============================================================================
__global__ __launch_bounds__(256, 4) void fused_all(
    const float* __restrict__ x,
    const float* __restrict__ lngi, const float* __restrict__ lnbi,
    const float* __restrict__ Wih, const float* __restrict__ Whh,
    const float* __restrict__ w1, const float* __restrict__ w2,
    const float* __restrict__ Wv, const float* __restrict__ Wq,
    const float* __restrict__ Wk,
    float* __restrict__ WihT, float* __restrict__ WhhT,
    float* __restrict__ w1T, float* __restrict__ w2T,
    float* __restrict__ WvT, float* __restrict__ WqkT,
    float* __restrict__ slots,
    const float* __restrict__ nbg, const float* __restrict__ nfg,
    const float* __restrict__ bgmu, const float* __restrict__ bgls,
    const float* __restrict__ fmu, const float* __restrict__ fls,
    const float* __restrict__ bih, const float* __restrict__ bhh,
    const float* __restrict__ lnmg, const float* __restrict__ lnmb,
    const float* __restrict__ b1, const float* __restrict__ b2,
    const float* __restrict__ sg, const float* __restrict__ sb,
    ushortT* __restrict__ qk_bf,
    float* __restrict__ pxn_p, float* __restrict__ den_p,
    float* __restrict__ outp) {
    cg::grid_group gg = cg::this_grid();
    int t = threadIdx.x, bid = blockIdx.x;
    int w = t >> 6, lane = t & 63, m = lane & 15, qd = lane >> 4;
    int bt = bid >> 3, cgrp = bid & 7;
    bool act = bid < 896;
    int b_s = bid / 7, s_s = bid % 7;

    __shared__ __align__(16) ushortT xnT[64 * 140];      // [e]*140 + row
    __shared__ __align__(16) ushortT p_lds[16][136];     // [slot][row]
    __shared__ float pxnL[64], hprevL[64], updL[64], giL[192], ghL[192],
                     mnL[64], m1L[128], xnL[64];
    __shared__ float denL;

    // ---- phase P: weight prep (blocks 0..207) ----
    if (bid < 192) {
        int i = bid * 256 + t;
        if (i < 12288) {
            int e = i >> 6, d = i & 63;
            WihT[d * 192 + e] = Wih[i];
        } else if (i < 24576) {
            int j = i - 12288; int e = j >> 6, d = j & 63;
            WhhT[d * 192 + e] = Whh[j];
        } else if (i < 32768) {
            int j = i - 24576; int e = j >> 6, d = j & 63;
            w1T[d * 128 + e] = w1[j];
        } else if (i < 40960) {
            int j = i - 32768; int e = j >> 7, h = j & 127;
            w2T[h * 64 + e] = w2[j];
        } else if (i < 45056) {
            int j = i - 40960; int d = j >> 6, e = j & 63;
            WvT[e * 64 + d] = Wv[j];
        }
    } else if (bid < 208) {
        int idx = (bid - 192) * 256 + t;
        int d = idx >> 6, tt2 = idx & 63;
        float acc = 0.f;
#pragma unroll 8
        for (int e = 0; e < 64; ++e) acc += Wk[e * 64 + tt2] * Wq[e * 64 + d];
        WqkT[d * 64 + tt2] = 0.125f * acc;
    }

    // ---- phase L: LN of this block's 512 rows -> regs (persist all iters) ----
    unsigned xw[4][2][8];   // [chunk][tile][word]: 0-3 = c0 dims, 4-7 = c1 dims
    {
        float4 g4[2][2], h4[2][2];
#pragma unroll
        for (int c = 0; c < 2; ++c) {
            g4[c][0] = *reinterpret_cast<const float4*>(lngi + c * 32 + qd * 8);
            g4[c][1] = *reinterpret_cast<const float4*>(lngi + c * 32 + qd * 8 + 4);
            h4[c][0] = *reinterpret_cast<const float4*>(lnbi + c * 32 + qd * 8);
            h4[c][1] = *reinterpret_cast<const float4*>(lnbi + c * 32 + qd * 8 + 4);
        }
#pragma unroll
        for (int c4 = 0; c4 < 4; ++c4)
#pragma unroll
            for (int tile = 0; tile < 2; ++tile) {
                long R = ((long)bt * 32 + cgrp * 4 + c4) * 128 + w * 32 + tile * 16 + m;
                float4 xa[2][2];
#pragma unroll
                for (int c = 0; c < 2; ++c) {
                    xa[c][0] = *reinterpret_cast<const float4*>(x + R * 64 + c * 32 + qd * 8);
                    xa[c][1] = *reinterpret_cast<const float4*>(x + R * 64 + c * 32 + qd * 8 + 4);
                }
                float s1 = 0.f, s2 = 0.f;
#pragma unroll
                for (int c = 0; c < 2; ++c)
#pragma unroll
                    for (int h = 0; h < 2; ++h) {
                        float4 v = xa[c][h];
                        s1 += v.x + v.y + v.z + v.w;
                        s2 += v.x * v.x + v.y * v.y + v.z * v.z + v.w * v.w;
                    }
                s1 += __shfl_xor(s1, 16); s2 += __shfl_xor(s2, 16);
                s1 += __shfl_xor(s1, 32); s2 += __shfl_xor(s2, 32);
                float mu = s1 * (1.f / 64.f);
                float var = s2 * (1.f / 64.f) - mu * mu;
                float rs = rsqrtf(var + LN_EPS);
#pragma unroll
                for (int c = 0; c < 2; ++c)
#pragma unroll
                    for (int h = 0; h < 2; ++h) {
                        float n0 = (xa[c][h].x - mu) * rs * g4[c][h].x + h4[c][h].x;
                        float n1 = (xa[c][h].y - mu) * rs * g4[c][h].y + h4[c][h].y;
                        float n2 = (xa[c][h].z - mu) * rs * g4[c][h].z + h4[c][h].z;
                        float n3 = (xa[c][h].w - mu) * rs * g4[c][h].w + h4[c][h].w;
                        xw[c4][tile][c * 4 + h * 2] =
                            (unsigned)f2bf(n0) | ((unsigned)f2bf(n1) << 16);
                        xw[c4][tile][c * 4 + h * 2 + 1] =
                            (unsigned)f2bf(n2) | ((unsigned)f2bf(n3) << 16);
                    }
            }
    }
    __threadfence(); gg.sync(); __threadfence();

    // ---- phase S0: slot init + first qk (blocks 0..895) ----
    {
        float res = 0.f;
        if (act && t < 64) {
            if (s_s == 0) res = bgmu[t] + __expf(bgls[t]) * nbg[b_s * 64 + t];
            else          res = fmu[t]  + __expf(fls[t])  * nfg[(b_s * 6 + s_s - 1) * 64 + t];
            slots[bid * 64 + t] = res;
            float mu, var;
            wave_stats64(res, mu, var);
            xnL[t] = (res - mu) * rsqrtf(var + LN_EPS) * sg[t] + sb[t];
        }
        __syncthreads();
        if (act && t < 64) {
            float qk = 0.f;
#pragma unroll 8
            for (int d = 0; d < 64; ++d) qk += xnL[d] * WqkT[d * 64 + t];
            qk_bf[b_s * 512 + s_s * 64 + t] = f2bf(qk);
            if (s_s == 0) qk_bf[b_s * 512 + 7 * 64 + t] = 0;
        }
    }
    __threadfence(); gg.sync(); __threadfence();

    // ---- iterations ----
    for (int it = 0; it < N_ITERS; ++it) {
        // A-frags: qk^T for my batch
        short8 aq0 = {}, aq1 = {};
        if (m < 8) {
            const ushortT* qb = qk_bf + bt * 512 + m * 64 + qd * 8;
            aq0 = *reinterpret_cast<const short8*>(qb);
            aq1 = *reinterpret_cast<const short8*>(qb + 32);
        }
        short8 ones;
#pragma unroll
        for (int j = 0; j < 8; ++j) ones[j] = (short)0x3F80;   // bf16 1.0
        floatx4 acc2 = {0.f, 0.f, 0.f, 0.f}, accd = {0.f, 0.f, 0.f, 0.f};

#pragma unroll
        for (int c4 = 0; c4 < 4; ++c4) {
            __syncthreads();   // xnT / p_lds free (prev chunk's phase2 done)
            // scatter xn chunk into xnT via pair-packed b32 writes
#pragma unroll
            for (int tile = 0; tile < 2; ++tile) {
                int Re = (w * 32 + tile * 16 + m) & ~1;
#pragma unroll
                for (int c = 0; c < 2; ++c) {
                    unsigned pt[4];
#pragma unroll
                    for (int k = 0; k < 4; ++k)
                        pt[k] = __shfl_xor(xw[c4][tile][c * 4 + k], 1);
#pragma unroll
                    for (int kk = 0; kk < 2; ++kk) {
                        unsigned own = (m & 1) ? xw[c4][tile][c * 4 + 2 + kk]
                                               : xw[c4][tile][c * 4 + kk];
                        unsigned par = (m & 1) ? pt[2 + kk] : pt[kk];
                        unsigned a   = (m & 1) ? par : own;   // even-row value
                        unsigned bo  = (m & 1) ? own : par;   // odd-row value
                        unsigned lo = (a & 0xffffu) | (bo << 16);
                        unsigned hi = (a >> 16)     | (bo & 0xffff0000u);
                        int e = c * 32 + qd * 8 + 2 * kk + ((m & 1) ? 4 : 0);
                        *reinterpret_cast<unsigned*>(&xnT[e * 140 + Re])       = lo;
                        *reinterpret_cast<unsigned*>(&xnT[(e + 1) * 140 + Re]) = hi;
                    }
                }
            }
            // phase 1: logits for both tiles (from regs)
            floatx4 accT0 = {0.f, 0.f, 0.f, 0.f}, accT1 = {0.f, 0.f, 0.f, 0.f};
            {
                uint4v b00 = {xw[c4][0][0], xw[c4][0][1], xw[c4][0][2], xw[c4][0][3]};
                uint4v b01 = {xw[c4][0][4], xw[c4][0][5], xw[c4][0][6], xw[c4][0][7]};
                accT0 = __builtin_amdgcn_mfma_f32_16x16x32_bf16(aq0,
                            __builtin_bit_cast(short8, b00), accT0, 0, 0, 0);
                accT0 = __builtin_amdgcn_mfma_f32_16x16x32_bf16(aq1,
                            __builtin_bit_cast(short8, b01), accT0, 0, 0, 0);
                uint4v b10 = {xw[c4][1][0], xw[c4][1][1], xw[c4][1][2], xw[c4][1][3]};
                uint4v b11 = {xw[c4][1][4], xw[c4][1][5], xw[c4][1][6], xw[c4][1][7]};
                accT1 = __builtin_amdgcn_mfma_f32_16x16x32_bf16(aq0,
                            __builtin_bit_cast(short8, b10), accT1, 0, 0, 0);
                accT1 = __builtin_amdgcn_mfma_f32_16x16x32_bf16(aq1,
                            __builtin_bit_cast(short8, b11), accT1, 0, 0, 0);
            }
            // tile-split softmax: every lane does ONE row's 7 slots
            float lgA[4], lgB[4];
#pragma unroll
            for (int r = 0; r < 4; ++r) {
                float hi = __shfl_xor(accT1[r], 32);
                float wk = (qd < 2) ? accT0[r] : hi;
                float pr = __shfl_xor(wk, 16);
                lgA[r] = (qd & 1) ? pr : wk;
                lgB[r] = (qd & 1) ? wk : pr;
            }
            float mx = fmaxf(fmaxf(fmaxf(lgA[0], lgA[1]), fmaxf(lgA[2], lgA[3])),
                             fmaxf(fmaxf(lgB[0], lgB[1]), lgB[2]));
            float eA[4], eB[3], sum = 0.f;
#pragma unroll
            for (int r = 0; r < 4; ++r) { eA[r] = __expf(lgA[r] - mx); sum += eA[r]; }
#pragma unroll
            for (int r = 0; r < 3; ++r) { eB[r] = __expf(lgB[r] - mx); sum += eB[r]; }
            float inv = 1.f / sum;
            int prow = w * 32 + (qd >> 1) * 16 + m;
            if ((qd & 1) == 0) {
#pragma unroll
                for (int r = 0; r < 4; ++r) p_lds[r][prow] = f2bf(eA[r] * inv + EPS_ATTN);
            } else {
#pragma unroll
                for (int r = 0; r < 3; ++r) p_lds[4 + r][prow] = f2bf(eB[r] * inv + EPS_ATTN);
            }
            __syncthreads();
            // phase 2: accumulate pxn / den partials over this chunk
#pragma unroll
            for (int ks = 0; ks < 4; ++ks) {
                short8 ap = *reinterpret_cast<const short8*>(&p_lds[m][ks * 32 + qd * 8]);
                const ushortT* xp = xnT + (w * 16 + m) * 140 + ks * 32 + qd * 8;
                uint2 u0 = *reinterpret_cast<const uint2*>(xp);
                uint2 u1 = *reinterpret_cast<const uint2*>(xp + 4);
                uint4v bbv = {u0.x, u0.y, u1.x, u1.y};
                acc2 = __builtin_amdgcn_mfma_f32_16x16x32_bf16(ap,
                           __builtin_bit_cast(short8, bbv), acc2, 0, 0, 0);
                accd = __builtin_amdgcn_mfma_f32_16x16x32_bf16(ap, ones, accd, 0, 0, 0);
            }
        }
        // write per-block partials
#pragma unroll
        for (int r = 0; r < 4; ++r) {
            int s = qd * 4 + r;
            if (s < 7) pxn_p[((long)bid * 7 + s) * 64 + w * 16 + m] = acc2[r];
        }
        if (w == 0 && m == 0) {
#pragma unroll
            for (int r = 0; r < 4; ++r) {
                int s = qd * 4 + r;
                if (s < 7) den_p[bid * 8 + s] = accd[r];
            }
        }
        __threadfence(); gg.sync(); __threadfence();

        // ---- slot phase (blocks 0..895, barriers uniform) ----
        if (act) {
            if (t < 64) {
                float psum = 0.f;
#pragma unroll
                for (int k = 0; k < 8; ++k)
                    psum += pxn_p[((long)(b_s * 8 + k) * 7 + s_s) * 64 + t];
                pxnL[t] = psum;
            } else if (t < 96) {
                int l = t - 64;
                float dv = (l < 8) ? den_p[(b_s * 8 + l) * 8 + s_s] : 0.f;
                dv += __shfl_xor(dv, 4, 8);
                dv += __shfl_xor(dv, 2, 8);
                dv += __shfl_xor(dv, 1, 8);
                if (l == 0) denL = dv;
            } else if (t >= 128 && t < 192) {
                hprevL[t - 128] = slots[bid * 64 + (t - 128)];
            }
        }
        __syncthreads();
        if (act && t < 64) {
            float nm = 0.f;
#pragma unroll 8
            for (int e = 0; e < 64; ++e) nm += pxnL[e] * WvT[e * 64 + t];
            updL[t] = nm / denL;
        }
        __syncthreads();
        if (act && t < 192) {
            float a = bih[t], h2 = bhh[t];
#pragma unroll 8
            for (int d = 0; d < 64; ++d) {
                a  += updL[d]   * WihT[d * 192 + t];
                h2 += hprevL[d] * WhhT[d * 192 + t];
            }
            giL[t] = a; ghL[t] = h2;
        }
        __syncthreads();
        float res = 0.f;
        if (act && t < 64) {
            float r = 1.f / (1.f + __expf(-(giL[t] + ghL[t])));
            float z = 1.f / (1.f + __expf(-(giL[64 + t] + ghL[64 + t])));
            float n = tanhf(giL[128 + t] + r * ghL[128 + t]);
            float h = (1.f - z) * n + z * hprevL[t];
            res = h;
            float mu, var;
            wave_stats64(h, mu, var);
            mnL[t] = (h - mu) * rsqrtf(var + LN_EPS) * lnmg[t] + lnmb[t];
        }
        __syncthreads();
        if (act && t < 128) {
            float a = b1[t];
#pragma unroll 8
            for (int d = 0; d < 64; ++d) a += mnL[d] * w1T[d * 128 + t];
            m1L[t] = fmaxf(a, 0.f);
        }
        __syncthreads();
        if (act && t < 64) {
            float a = b2[t];
#pragma unroll 8
            for (int h2 = 0; h2 < 128; ++h2) a += m1L[h2] * w2T[h2 * 64 + t];
            res += a;
            slots[bid * 64 + t] = res;
        }
        if (it == N_ITERS - 1) {
            if (act && t < 64) outp[bid * 64 + t] = res;
        } else {
            if (act && t < 64) {
                float mu, var;
                wave_stats64(res, mu, var);
                xnL[t] = (res - mu) * rsqrtf(var + LN_EPS) * sg[t] + sb[t];
            }
            __syncthreads();
            if (act && t < 64) {
                float qk = 0.f;
#pragma unroll 8
                for (int d = 0; d < 64; ++d) qk += xnL[d] * WqkT[d * 64 + t];
                qk_bf[b_s * 512 + s_s * 64 + t] = f2bf(qk);
                if (s_s == 0) qk_bf[b_s * 512 + 7 * 64 + t] = 0;
            }
            __threadfence(); gg.sync(); __threadfence();
        }
    }
}

// ============================================================================
// Fallback path (exact R3 kernels, 352.9 µs proven) — used if cooperative
// launch is unavailable or rejected.
// ============================================================================
__global__ void prep_w(const float* __restrict__ Wih, const float* __restrict__ Whh,
                       const float* __restrict__ w1, const float* __restrict__ w2,
                       const float* __restrict__ Wv, const float* __restrict__ Wq,
                       const float* __restrict__ Wk,
                       float* __restrict__ WihT, float* __restrict__ WhhT,
                       float* __restrict__ w1T, float* __restrict__ w2T,
                       float* __restrict__ WvT, float* __restrict__ WqkT) {
    if (blockIdx.x >= 192) {
        int idx = (blockIdx.x - 192) * 256 + threadIdx.x;
        int d = idx >> 6, tt = idx & 63;
        float acc = 0.f;
#pragma unroll 8
        for (int e = 0; e < 64; ++e) acc += Wk[e * 64 + tt] * Wq[e * 64 + d];
        WqkT[d * 64 + tt] = 0.125f * acc;
        return;
    }
    int i = blockIdx.x * 256 + threadIdx.x;
    if (i < 12288) {
        int e = i >> 6, d = i & 63;
        WihT[d * 192 + e] = Wih[i];
    } else if (i < 24576) {
        int j = i - 12288; int e = j >> 6, d = j & 63;
        WhhT[d * 192 + e] = Whh[j];
    } else if (i < 32768) {
        int j = i - 24576; int e = j >> 6, d = j & 63;
        w1T[d * 128 + e] = w1[j];
    } else if (i < 40960) {
        int j = i - 32768; int e = j >> 7, h = j & 127;
        w2T[h * 64 + e] = w2[j];
    } else if (i < 45056) {
        int j = i - 40960; int d = j >> 6, e = j & 63;
        WvT[e * 64 + d] = Wv[j];
    }
}

__global__ __launch_bounds__(256) void attn_kernel(
    int first,
    const float* __restrict__ x,
    const float* __restrict__ lng, const float* __restrict__ lnb,
    ushortT* __restrict__ xnf,
    const ushortT* __restrict__ qk_bf,
    float* __restrict__ pxn_p, float* __restrict__ den_p) {
    int t = threadIdx.x;
    int ck = blockIdx.x, b = ck >> 5;
    int w = t >> 6, lane = t & 63, m = lane & 15, qd = lane >> 4;
    __shared__ __align__(16) ushortT xnT[64 * 140];
    __shared__ __align__(16) ushortT p_lds[16][136];

    short8 aq0 = {}, aq1 = {};
    if (m < 8) {
        const ushortT* qb = qk_bf + b * 512 + m * 64 + qd * 8;
        aq0 = *reinterpret_cast<const short8*>(qb);
        aq1 = *reinterpret_cast<const short8*>(qb + 32);
    }
    unsigned xw[2][8];
    if (first) {
        float4 g4[2][2], b4[2][2];
#pragma unroll
        for (int c = 0; c < 2; ++c) {
            g4[c][0] = *reinterpret_cast<const float4*>(lng + c * 32 + qd * 8);
            g4[c][1] = *reinterpret_cast<const float4*>(lng + c * 32 + qd * 8 + 4);
            b4[c][0] = *reinterpret_cast<const float4*>(lnb + c * 32 + qd * 8);
            b4[c][1] = *reinterpret_cast<const float4*>(lnb + c * 32 + qd * 8 + 4);
        }
#pragma unroll
        for (int tile = 0; tile < 2; ++tile) {
            long R = (long)ck * 128 + w * 32 + tile * 16 + m;
            float4 xa[2][2];
#pragma unroll
            for (int c = 0; c < 2; ++c) {
                xa[c][0] = *reinterpret_cast<const float4*>(x + R * 64 + c * 32 + qd * 8);
                xa[c][1] = *reinterpret_cast<const float4*>(x + R * 64 + c * 32 + qd * 8 + 4);
            }
            float s1 = 0.f, s2 = 0.f;
#pragma unroll
            for (int c = 0; c < 2; ++c)
#pragma unroll
                for (int h = 0; h < 2; ++h) {
                    float4 v = xa[c][h];
                    s1 += v.x + v.y + v.z + v.w;
                    s2 += v.x * v.x + v.y * v.y + v.z * v.z + v.w * v.w;
                }
            s1 += __shfl_xor(s1, 16); s2 += __shfl_xor(s2, 16);
            s1 += __shfl_xor(s1, 32); s2 += __shfl_xor(s2, 32);
            float mu = s1 * (1.f / 64.f);
            float var = s2 * (1.f / 64.f) - mu * mu;
            float rs = rsqrtf(var + LN_EPS);
#pragma unroll
            for (int c = 0; c < 2; ++c)
#pragma unroll
                for (int h = 0; h < 2; ++h) {
                    float n0 = (xa[c][h].x - mu) * rs * g4[c][h].x + b4[c][h].x;
                    float n1 = (xa[c][h].y - mu) * rs * g4[c][h].y + b4[c][h].y;
                    float n2 = (xa[c][h].z - mu) * rs * g4[c][h].z + b4[c][h].z;
                    float n3 = (xa[c][h].w - mu) * rs * g4[c][h].w + b4[c][h].w;
                    xw[tile][c * 4 + h * 2]     = (unsigned)f2bf(n0) | ((unsigned)f2bf(n1) << 16);
                    xw[tile][c * 4 + h * 2 + 1] = (unsigned)f2bf(n2) | ((unsigned)f2bf(n3) << 16);
                }
            ushortT* xp = xnf + (long)ck * 8192 + w * 2048 + tile * 1024 + lane * 16;
            *reinterpret_cast<uint4*>(xp) =
                make_uint4(xw[tile][0], xw[tile][1], xw[tile][2], xw[tile][3]);
            *reinterpret_cast<uint4*>(xp + 8) =
                make_uint4(xw[tile][4], xw[tile][5], xw[tile][6], xw[tile][7]);
        }
    } else {
#pragma unroll
        for (int tile = 0; tile < 2; ++tile) {
            const ushortT* xp = xnf + (long)ck * 8192 + w * 2048 + tile * 1024 + lane * 16;
            uint4 u0 = *reinterpret_cast<const uint4*>(xp);
            uint4 u1 = *reinterpret_cast<const uint4*>(xp + 8);
            xw[tile][0] = u0.x; xw[tile][1] = u0.y; xw[tile][2] = u0.z; xw[tile][3] = u0.w;
            xw[tile][4] = u1.x; xw[tile][5] = u1.y; xw[tile][6] = u1.z; xw[tile][7] = u1.w;
        }
    }
#pragma unroll
    for (int tile = 0; tile < 2; ++tile) {
        int Re = (w * 32 + tile * 16 + m) & ~1;
#pragma unroll
        for (int c = 0; c < 2; ++c) {
            unsigned pt[4];
#pragma unroll
            for (int k = 0; k < 4; ++k) pt[k] = __shfl_xor(xw[tile][c * 4 + k], 1);
#pragma unroll
            for (int kk = 0; kk < 2; ++kk) {
                unsigned own = (m & 1) ? xw[tile][c * 4 + 2 + kk] : xw[tile][c * 4 + kk];
                unsigned par = (m & 1) ? pt[2 + kk] : pt[kk];
                unsigned a   = (m & 1) ? par : own;
                unsigned bb  = (m & 1) ? own : par;
                unsigned lo = (a & 0xffffu) | (bb << 16);
                unsigned hi = (a >> 16)     | (bb & 0xffff0000u);
                int e = c * 32 + qd * 8 + 2 * kk + ((m & 1) ? 4 : 0);
                *reinterpret_cast<unsigned*>(&xnT[e * 140 + Re])       = lo;
                *reinterpret_cast<unsigned*>(&xnT[(e + 1) * 140 + Re]) = hi;
            }
        }
    }
    floatx4 accT0 = {0.f, 0.f, 0.f, 0.f}, accT1 = {0.f, 0.f, 0.f, 0.f};
    {
        uint4v b00 = {xw[0][0], xw[0][1], xw[0][2], xw[0][3]};
        uint4v b01 = {xw[0][4], xw[0][5], xw[0][6], xw[0][7]};
        accT0 = __builtin_amdgcn_mfma_f32_16x16x32_bf16(aq0,
                    __builtin_bit_cast(short8, b00), accT0, 0, 0, 0);
        accT0 = __builtin_amdgcn_mfma_f32_16x16x32_bf16(aq1,
                    __builtin_bit_cast(short8, b01), accT0, 0, 0, 0);
        uint4v b10 = {xw[1][0], xw[1][1], xw[1][2], xw[1][3]};
        uint4v b11 = {xw[1][4], xw[1][5], xw[1][6], xw[1][7]};
        accT1 = __builtin_amdgcn_mfma_f32_16x16x32_bf16(aq0,
                    __builtin_bit_cast(short8, b10), accT1, 0, 0, 0);
        accT1 = __builtin_amdgcn_mfma_f32_16x16x32_bf16(aq1,
                    __builtin_bit_cast(short8, b11), accT1, 0, 0, 0);
    }
    float lgA[4], lgB[4];
#pragma unroll
    for (int r = 0; r < 4; ++r) {
        float hi = __shfl_xor(accT1[r], 32);
        float wk = (qd < 2) ? accT0[r] : hi;
        float pr = __shfl_xor(wk, 16);
        lgA[r] = (qd & 1) ? pr : wk;
        lgB[r] = (qd & 1) ? wk : pr;
    }
    float mx = fmaxf(fmaxf(fmaxf(lgA[0], lgA[1]), fmaxf(lgA[2], lgA[3])),
                     fmaxf(fmaxf(lgB[0], lgB[1]), lgB[2]));
    float eA[4], eB[3], sum = 0.f;
#pragma unroll
    for (int r = 0; r < 4; ++r) { eA[r] = __expf(lgA[r] - mx); sum += eA[r]; }
#pragma unroll
    for (int r = 0; r < 3; ++r) { eB[r] = __expf(lgB[r] - mx); sum += eB[r]; }
    float inv = 1.f / sum;
    int prow = w * 32 + (qd >> 1) * 16 + m;
    if ((qd & 1) == 0) {
#pragma unroll
        for (int r = 0; r < 4; ++r) p_lds[r][prow] = f2bf(eA[r] * inv + EPS_ATTN);
    } else {
#pragma unroll
        for (int r = 0; r < 3; ++r) p_lds[4 + r][prow] = f2bf(eB[r] * inv + EPS_ATTN);
    }
    __syncthreads();
    short8 ones;
#pragma unroll
    for (int j = 0; j < 8; ++j) ones[j] = (short)0x3F80;
    floatx4 acc2 = {0.f, 0.f, 0.f, 0.f}, accd = {0.f, 0.f, 0.f, 0.f};
#pragma unroll
    for (int ks = 0; ks < 4; ++ks) {
        short8 ap = *reinterpret_cast<const short8*>(&p_lds[m][ks * 32 + qd * 8]);
        const ushortT* xp = xnT + (w * 16 + m) * 140 + ks * 32 + qd * 8;
        uint2 u0 = *reinterpret_cast<const uint2*>(xp);
        uint2 u1 = *reinterpret_cast<const uint2*>(xp + 4);
        uint4v bb = {u0.x, u0.y, u1.x, u1.y};
        acc2 = __builtin_amdgcn_mfma_f32_16x16x32_bf16(ap,
                   __builtin_bit_cast(short8, bb), acc2, 0, 0, 0);
        accd = __builtin_amdgcn_mfma_f32_16x16x32_bf16(ap, ones, accd, 0, 0, 0);
    }
#pragma unroll
    for (int r = 0; r < 4; ++r) {
        int s = qd * 4 + r;
        if (s < 7) pxn_p[((long)ck * 7 + s) * 64 + w * 16 + m] = acc2[r];
    }
    if (w == 0 && m == 0) {
#pragma unroll
        for (int r = 0; r < 4; ++r) {
            int s = qd * 4 + r;
            if (s < 7) den_p[ck * 8 + s] = accd[r];
        }
    }
}

__global__ __launch_bounds__(192) void slot_update_q(
    int mode,
    const float* __restrict__ pxn_p, const float* __restrict__ den_p,
    float* __restrict__ slots,
    const float* __restrict__ nbg, const float* __restrict__ nfg,
    const float* __restrict__ bgmu, const float* __restrict__ bgls,
    const float* __restrict__ fmu, const float* __restrict__ fls,
    const float* __restrict__ WihT, const float* __restrict__ WhhT,
    const float* __restrict__ bih, const float* __restrict__ bhh,
    const float* __restrict__ lng, const float* __restrict__ lnb,
    const float* __restrict__ w1T, const float* __restrict__ b1,
    const float* __restrict__ w2T, const float* __restrict__ b2,
    const float* __restrict__ WvT, const float* __restrict__ WqkT,
    const float* __restrict__ sg, const float* __restrict__ sb,
    ushortT* __restrict__ qk_bf, float* __restrict__ outp) {
    int bs = blockIdx.x, t = threadIdx.x;
    int b = bs / 7, s = bs % 7;
    __shared__ float pxnL[64], hprevL[64], updL[64], giL[192], ghL[192],
                     mnL[64], m1L[128], xnL[64];
    __shared__ float denL;
    float res = 0.f;
    if (mode == 0) {
        if (t < 64) {
            if (s == 0) res = bgmu[t] + __expf(bgls[t]) * nbg[b * 64 + t];
            else        res = fmu[t]  + __expf(fls[t])  * nfg[(b * 6 + s - 1) * 64 + t];
        }
    } else {
        if (t < 64) {
            float psum = 0.f;
#pragma unroll 8
            for (int c = 0; c < 32; ++c)
                psum += pxn_p[((long)(b * 32 + c) * 7 + s) * 64 + t];
            pxnL[t] = psum;
        } else if (t < 96) {
            float dv = den_p[(b * 32 + (t - 64)) * 8 + s];
#pragma unroll
            for (int off = 16; off > 0; off >>= 1) dv += __shfl_xor(dv, off, 32);
            if (t == 64) denL = dv;
        } else if (t >= 128) {
            hprevL[t - 128] = slots[bs * 64 + (t - 128)];
        }
        __syncthreads();
        if (t < 64) {
            float nm = 0.f;
#pragma unroll 8
            for (int e = 0; e < 64; ++e) nm += pxnL[e] * WvT[e * 64 + t];
            updL[t] = nm / denL;
        }
        __syncthreads();
        {
            float a = bih[t], h2 = bhh[t];
#pragma unroll 8
            for (int d = 0; d < 64; ++d) {
                a  += updL[d]   * WihT[d * 192 + t];
                h2 += hprevL[d] * WhhT[d * 192 + t];
            }
            giL[t] = a; ghL[t] = h2;
        }
        __syncthreads();
        if (t < 64) {
            float r = 1.f / (1.f + __expf(-(giL[t] + ghL[t])));
            float z = 1.f / (1.f + __expf(-(giL[64 + t] + ghL[64 + t])));
            float n = tanhf(giL[128 + t] + r * ghL[128 + t]);
            float h = (1.f - z) * n + z * hprevL[t];
            res = h;
            float mu, var;
            wave_stats64(h, mu, var);
            mnL[t] = (h - mu) * rsqrtf(var + LN_EPS) * lng[t] + lnb[t];
        }
        __syncthreads();
        if (t < 128) {
            float a = b1[t];
#pragma unroll 8
            for (int d = 0; d < 64; ++d) a += mnL[d] * w1T[d * 128 + t];
            m1L[t] = fmaxf(a, 0.f);
        }
        __syncthreads();
        if (t < 64) {
            float a = b2[t];
#pragma unroll 8
            for (int h2 = 0; h2 < 128; ++h2) a += m1L[h2] * w2T[h2 * 64 + t];
            res += a;
        }
    }
    if (t < 64) slots[bs * 64 + t] = res;
    if (mode == 2) {
        if (t < 64) outp[bs * 64 + t] = res;
        return;
    }
    if (t < 64) {
        float mu, var;
        wave_stats64(res, mu, var);
        xnL[t] = (res - mu) * rsqrtf(var + LN_EPS) * sg[t] + sb[t];
    }
    __syncthreads();
    if (t < 64) {
        float qk = 0.f;
#pragma unroll 8
        for (int d = 0; d < 64; ++d) qk += xnL[d] * WqkT[d * 64 + t];
        qk_bf[b * 512 + s * 64 + t] = f2bf(qk);
        if (s == 0) qk_bf[b * 512 + 7 * 64 + t] = 0;
    }
}

// ---------------- launcher ----------------
extern "C" void kernel_launch(void* const* d_in, const int* in_sizes, int n_in,
                              void* d_out, int out_size, void* d_ws, size_t ws_size,
                              hipStream_t stream) {
    const float* inputs    = (const float*)d_in[0];
    const float* noise_bg  = (const float*)d_in[1];
    const float* noise_fg  = (const float*)d_in[2];
    const float* ln_in_g   = (const float*)d_in[3];
    const float* ln_in_b   = (const float*)d_in[4];
    const float* ln_slot_g = (const float*)d_in[5];
    const float* ln_slot_b = (const float*)d_in[6];
    const float* ln_mlp_g  = (const float*)d_in[7];
    const float* ln_mlp_b  = (const float*)d_in[8];
    const float* Wq        = (const float*)d_in[9];
    const float* Wk        = (const float*)d_in[10];
    const float* Wv        = (const float*)d_in[11];
    const float* W_ih      = (const float*)d_in[12];
    const float* W_hh      = (const float*)d_in[13];
    const float* b_ih      = (const float*)d_in[14];
    const float* b_hh      = (const float*)d_in[15];
    const float* mlp_w1    = (const float*)d_in[16];
    const float* mlp_b1    = (const float*)d_in[17];
    const float* mlp_w2    = (const float*)d_in[18];
    const float* mlp_b2    = (const float*)d_in[19];
    const float* sbg_mu    = (const float*)d_in[20];
    const float* sbg_ls    = (const float*)d_in[21];
    const float* s_mu      = (const float*)d_in[22];
    const float* s_ls      = (const float*)d_in[23];

    char* ws = (char*)d_ws;
    size_t off = 0;
    auto alloc = [&](size_t bytes) {
        void* p = ws + off;
        off += (bytes + 255) & ~(size_t)255;
        return p;
    };
    ushortT* xnf   = (ushortT*)alloc((size_t)BB * NN * 64 * 2);   // fallback only
    float* slots   = (float*)alloc(57344 * 4);
    ushortT* qk_bf = (ushortT*)alloc((size_t)BB * 512 * 2);
    float* pxn_p   = (float*)alloc((size_t)4096 * 7 * 64 * 4);
    float* den_p   = (float*)alloc(4096 * 8 * 4);
    float* WihT    = (float*)alloc(12288 * 4);
    float* WhhT    = (float*)alloc(12288 * 4);
    float* w1T     = (float*)alloc(8192 * 4);
    float* w2T     = (float*)alloc(8192 * 4);
    float* WvT     = (float*)alloc(4096 * 4);
    float* WqkT    = (float*)alloc(4096 * 4);
    if (off > ws_size) return;
    float* outp = (float*)d_out;

    static int coop_ok = -1;
    if (coop_ok < 0) {
        int dev = 0, v = 0;
        hipGetDevice(&dev);
        hipDeviceGetAttribute(&v, hipDeviceAttributeCooperativeLaunch, dev);
        coop_ok = v;
    }
    if (coop_ok) {
        void* args[] = {
            (void*)&inputs, (void*)&ln_in_g, (void*)&ln_in_b,
            (void*)&W_ih, (void*)&W_hh, (void*)&mlp_w1, (void*)&mlp_w2,
            (void*)&Wv, (void*)&Wq, (void*)&Wk,
            (void*)&WihT, (void*)&WhhT, (void*)&w1T, (void*)&w2T,
            (void*)&WvT, (void*)&WqkT,
            (void*)&slots,
            (void*)&noise_bg, (void*)&noise_fg, (void*)&sbg_mu, (void*)&sbg_ls,
            (void*)&s_mu, (void*)&s_ls,
            (void*)&b_ih, (void*)&b_hh,
            (void*)&ln_mlp_g, (void*)&ln_mlp_b,
            (void*)&mlp_b1, (void*)&mlp_b2,
            (void*)&ln_slot_g, (void*)&ln_slot_b,
            (void*)&qk_bf,
            (void*)&pxn_p, (void*)&den_p,
            (void*)&outp
        };
        hipError_t e = hipLaunchCooperativeKernel((const void*)fused_all,
                                                  dim3(1024), dim3(256),
                                                  args, 0, stream);
        if (e == hipSuccess) return;
        coop_ok = 0;   // fall through to the proven multi-dispatch path
    }

    prep_w<<<208, 256, 0, stream>>>(W_ih, W_hh, mlp_w1, mlp_w2, Wv, Wq, Wk,
                                    WihT, WhhT, w1T, w2T, WvT, WqkT);
    slot_update_q<<<896, 192, 0, stream>>>(0, pxn_p, den_p, slots,
                                           noise_bg, noise_fg, sbg_mu, sbg_ls,
                                           s_mu, s_ls, WihT, WhhT, b_ih, b_hh,
                                           ln_mlp_g, ln_mlp_b, w1T, mlp_b1,
                                           w2T, mlp_b2, WvT, WqkT,
                                           ln_slot_g, ln_slot_b,
                                           qk_bf, outp);
    for (int it = 0; it < N_ITERS; ++it) {
        attn_kernel<<<4096, 256, 0, stream>>>((it == 0) ? 1 : 0,
                                              inputs, ln_in_g, ln_in_b,
                                              xnf, qk_bf, pxn_p, den_p);
        slot_update_q<<<896, 192, 0, stream>>>((it == N_ITERS - 1) ? 2 : 1,
                                               pxn_p, den_p, slots,
                                               noise_bg, noise_fg, sbg_mu, sbg_ls,
                                               s_mu, s_ls, WihT, WhhT, b_ih, b_hh,
                                               ln_mlp_g, ln_mlp_b, w1T, mlp_b1,
                                               w2T, mlp_b2, WvT, WqkT,
                                               ln_slot_g, ln_slot_b,
                                               qk_bf, outp);
    }
}